// Round 12
// baseline (7164.709 us; speedup 1.0000x reference)
//
#include <hip/hip_runtime.h>
#include <hip/hip_bf16.h>
#include <math.h>
#include <type_traits>

#define HIDDEN 256
#define SEQ 2048
#define BATCH 64
#define INSZ 128
#define OUTSZ 64
#define DTC 0.05f
#define LROW 264   // LDS h row stride in f16 units (528 B): phase-conflict-free

typedef _Float16 f16x8 __attribute__((ext_vector_type(8)));
typedef float f32x4 __attribute__((ext_vector_type(4)));

// ---------------- K0: complexity net + alphas ----------------
__global__ __launch_bounds__(1024) void prep_kernel(
    const float* __restrict__ x, const float* __restrict__ cw1, const float* __restrict__ cb1,
    const float* __restrict__ cw2, const float* __restrict__ cb2,
    const float* __restrict__ tau_b, const float* __restrict__ tmw, const float* __restrict__ tmb,
    float* __restrict__ alphas)   // [3][64]
{
    __shared__ float p_lds[8][128];
    __shared__ float xm[128];
    __shared__ float t1[64];
    int b = blockIdx.x;
    int tid = threadIdx.x;
    int c = tid & 127, sh = tid >> 7;
    const float* xb = x + (size_t)b * SEQ * INSZ;
    float s = 0.f;
    for (int t = sh * 256; t < (sh + 1) * 256; ++t) s += xb[(size_t)t * INSZ + c];
    p_lds[sh][c] = s;
    __syncthreads();
    if (tid < 128) {
        float m = 0.f;
        #pragma unroll
        for (int i = 0; i < 8; ++i) m += p_lds[i][tid];
        xm[tid] = m / (float)SEQ;
    }
    __syncthreads();
    if (tid < 64) {
        float acc = cb1[tid];
        for (int k = 0; k < 128; ++k) acc += xm[k] * cw1[tid * 128 + k];
        t1[tid] = fmaxf(acc, 0.f);
    }
    __syncthreads();
    if (tid == 0) {
        float acc = cb2[0];
        for (int k = 0; k < 64; ++k) acc += t1[k] * cw2[k];
        float comp = 1.f / (1.f + expf(-acc));
        for (int i = 0; i < 3; ++i) {
            float lg[4], mx = -1e30f;
            for (int j = 0; j < 4; ++j) { lg[j] = comp * tmw[i * 4 + j] + tmb[i * 4 + j]; mx = fmaxf(mx, lg[j]); }
            float den = 0.f;
            for (int j = 0; j < 4; ++j) { lg[j] = expf(lg[j] - mx); den += lg[j]; }
            float mt = 0.f;
            for (int j = 0; j < 4; ++j) mt += tau_b[i * 4 + j] * (lg[j] / den);
            alphas[i * 64 + b] = expf(-DTC / mt);
        }
    }
}

// ---------------- Wf = W_in0 @ pw  (256x128), bf = W_in0 @ pb + bias0 ----------------
__global__ __launch_bounds__(128) void wf_kernel(
    const float* __restrict__ W_in0, const float* __restrict__ pw,
    const float* __restrict__ pb, const float* __restrict__ bias0,
    float* __restrict__ Wf, float* __restrict__ bf)
{
    __shared__ float wrow[256];
    int j = blockIdx.x, k = threadIdx.x;
    for (int m = k; m < 256; m += 128) wrow[m] = W_in0[j * 256 + m];
    __syncthreads();
    float s = 0.f;
    for (int m = 0; m < 256; ++m) s = fmaf(wrow[m], pw[m * 128 + k], s);
    Wf[j * 128 + k] = s;
    if (k == 0) {
        float sb = bias0[j];
        for (int m = 0; m < 256; ++m) sb = fmaf(wrow[m], pb[m], sb);
        bf[j] = sb;
    }
}

// ---------------- streaming register-weight GEMM (unchanged, fp32) ----------------
template<int KQ, int NR>
__global__ __launch_bounds__(512) void gemm_stream(
    const float* A, const float* __restrict__ W, const float* __restrict__ bias,
    float* C, int rows_per_wg)
{
    constexpr int K = KQ * 64;
    constexpr int JB = 8 / KQ;
    __shared__ float a_lds[4 * K];
    __shared__ float p_lds[KQ][4][256];
    __shared__ float bias_l[256];
    int tid = threadIdx.x;
    int w = tid >> 6, l = tid & 63;
    int q = w % KQ, jb = w / KQ;

    float4 wr[NR][16];
    #pragma unroll
    for (int r = 0; r < NR; ++r) {
        int j = jb * 64 + l + r * (JB * 64);
        const float4* wp = (const float4*)(W + (size_t)j * K + q * 64);
        #pragma unroll
        for (int m = 0; m < 16; ++m) wr[r][m] = wp[m];
    }
    if (tid < 256) bias_l[tid] = bias[tid];

    size_t row0 = (size_t)blockIdx.x * rows_per_wg;
    for (int it = 0; it < rows_per_wg; it += 4) {
        size_t m0 = row0 + it;
        __syncthreads();
        #pragma unroll
        for (int e = 0; e < K / 128; ++e)
            a_lds[tid + e * 512] = A[m0 * K + tid + e * 512];
        __syncthreads();

        float acc[4][NR];
        #pragma unroll
        for (int r4 = 0; r4 < 4; ++r4)
            #pragma unroll
            for (int r = 0; r < NR; ++r) acc[r4][r] = 0.f;

        #pragma unroll
        for (int r4 = 0; r4 < 4; ++r4) {
            const float4* hp = (const float4*)(a_lds + r4 * K + q * 64);
            #pragma unroll
            for (int m = 0; m < 16; ++m) {
                float4 hv = hp[m];
                #pragma unroll
                for (int r = 0; r < NR; ++r) {
                    acc[r4][r] = fmaf(wr[r][m].x, hv.x, acc[r4][r]);
                    acc[r4][r] = fmaf(wr[r][m].y, hv.y, acc[r4][r]);
                    acc[r4][r] = fmaf(wr[r][m].z, hv.z, acc[r4][r]);
                    acc[r4][r] = fmaf(wr[r][m].w, hv.w, acc[r4][r]);
                }
            }
        }
        #pragma unroll
        for (int r4 = 0; r4 < 4; ++r4)
            #pragma unroll
            for (int r = 0; r < NR; ++r)
                p_lds[q][r4][jb * 64 + l + r * (JB * 64)] = acc[r4][r];
        __syncthreads();
        if (tid < 256) {
            #pragma unroll
            for (int r4 = 0; r4 < 4; ++r4) {
                float s2 = bias_l[tid];
                #pragma unroll
                for (int qq = 0; qq < KQ; ++qq) s2 += p_lds[qq][r4][tid];
                C[(m0 + r4) * 256 + tid] = s2;
            }
        }
    }
}

__device__ __forceinline__ float fast_tanh(float x) {
    float ex = __expf(2.f * x);                 // v_exp based
    float r = __builtin_amdgcn_rcpf(ex + 1.f);  // v_rcp_f32
    return 1.f - 2.f * r;                       // ex=inf -> 1, ex=0 -> -1
}

__device__ __forceinline__ unsigned pkrtz(float a, float b) {
    return __builtin_bit_cast(unsigned, __builtin_amdgcn_cvt_pkrtz(a, b));
}

// LDS-only barrier: waits ds ops (lgkmcnt) but leaves global loads/stores in flight.
__device__ __forceinline__ void barrier_lds_only() {
    asm volatile("s_waitcnt lgkmcnt(0)\n\ts_barrier" ::: "memory");
}

// ---------------- MFMA scan: 4 WGs x 16 batch, S = W_rec @ H via matrix pipe ----------------
// Wave w owns outputs m in [w*64, w*64+64) (4 m-tiles of 16). H in LDS as [b][k] f16,
// row stride LROW=264 f16 (528B). Fragments (16x16x32 f16):
//   A: m=lane&15, k=8*(lane>>4)+e   (W_rec, preloaded, AGPR-resident)
//   B: n=lane&15, k=8*(lane>>4)+e   (H, contiguous 16B -> ds_read_b128)
//   D: n=lane&15, m=(lane>>4)*4+reg (per m89-corrected layout)
// Every lane's outputs share one batch b = wg*16 + (lane&15) -> uniform alpha.
__global__ __launch_bounds__(256, 1) void scan_kernel(
    float* buf,                       // [B][S][256]: in = ext, out = h_seq (in place)
    const float* __restrict__ W_rec,  // [256][256]
    const float* __restrict__ alphas, // [64]
    float* __restrict__ h_carry,      // [64][256]
    int layer, int write_all)
{
    __shared__ alignas(16) _Float16 hlds[2][16 * LROW];  // 2 x 8448 B
    const int tid = threadIdx.x;
    const int wave = tid >> 6, lane = tid & 63;
    const int bl = lane & 15, q = lane >> 4;
    const int b = blockIdx.x * 16 + bl;

    // ---- A fragments: W rows [wave*64, wave*64+64), 4 m-tiles x 8 k-tiles ----
    f16x8 afrag[4][8];
    #pragma unroll
    for (int mt = 0; mt < 4; ++mt) {
        const float* wr = W_rec + (size_t)(wave * 64 + mt * 16 + bl) * 256;
        #pragma unroll
        for (int kt = 0; kt < 8; ++kt) {
            const float4* wp = (const float4*)(wr + kt * 32 + q * 8);
            float4 wa = wp[0], wb = wp[1];
            uint4 u = { pkrtz(wa.x, wa.y), pkrtz(wa.z, wa.w),
                        pkrtz(wb.x, wb.y), pkrtz(wb.z, wb.w) };
            afrag[mt][kt] = __builtin_bit_cast(f16x8, u);
        }
    }

    const float alpha = alphas[b], onema = 1.f - alpha;
    float* bb = buf + (size_t)b * SEQ * HIDDEN;

    // ---- h registers: 4 m-tiles x 4 outputs, o0 = wave*64 + mt*16 + q*4 ----
    f32x4 hreg[4];
    #pragma unroll
    for (int mt = 0; mt < 4; ++mt) {
        if (layer == 0) hreg[mt] = (f32x4){0.f, 0.f, 0.f, 0.f};
        else hreg[mt] = *(const f32x4*)(h_carry + b * 256 + wave * 64 + mt * 16 + q * 4);
    }

    char* hb0 = (char*)&hlds[0][0];
    char* hb1 = (char*)&hlds[1][0];
    const int rdoff = (bl * LROW + q * 8) * 2;                    // + kt*64 bytes
    const int wroff = (bl * LROW + wave * 64 + q * 4) * 2;        // + mt*32 bytes

    // init h into LDS buffer 0
    #pragma unroll
    for (int mt = 0; mt < 4; ++mt) {
        uint2 p = { pkrtz(hreg[mt][0], hreg[mt][1]), pkrtz(hreg[mt][2], hreg[mt][3]) };
        *(uint2*)(hb0 + wroff + mt * 32) = p;
    }

    // ext prefetch, 2-ahead: ec = ext[t], e1 = ext[t+1]
    f32x4 ec[4], e1[4];
    const float* ep = bb + wave * 64 + q * 4;
    #pragma unroll
    for (int mt = 0; mt < 4; ++mt) {
        ec[mt] = *(const f32x4*)(ep + mt * 16);
        e1[mt] = *(const f32x4*)(ep + 256 + mt * 16);
    }
    ep += 512;
    float* sp = bb + wave * 64 + q * 4;
    __syncthreads();

    auto step = [&](auto CB, int t) {
        constexpr int CUR = decltype(CB)::value;
        char* rb = (CUR == 0) ? hb0 : hb1;
        char* wb = (CUR == 0) ? hb1 : hb0;
        // B fragments: 8 x ds_read_b128, issued back-to-back
        uint4 bq0 = *(const uint4*)(rb + rdoff);
        uint4 bq1 = *(const uint4*)(rb + rdoff + 64);
        uint4 bq2 = *(const uint4*)(rb + rdoff + 128);
        uint4 bq3 = *(const uint4*)(rb + rdoff + 192);
        uint4 bq4 = *(const uint4*)(rb + rdoff + 256);
        uint4 bq5 = *(const uint4*)(rb + rdoff + 320);
        uint4 bq6 = *(const uint4*)(rb + rdoff + 384);
        uint4 bq7 = *(const uint4*)(rb + rdoff + 448);

        f32x4 e2[4];
        if (t + 2 < SEQ) {
            #pragma unroll
            for (int mt = 0; mt < 4; ++mt) e2[mt] = *(const f32x4*)(ep + mt * 16);
        } else {
            #pragma unroll
            for (int mt = 0; mt < 4; ++mt) e2[mt] = (f32x4){0.f, 0.f, 0.f, 0.f};
        }
        ep += 256;

        f32x4 a0 = {0.f,0.f,0.f,0.f}, a1 = {0.f,0.f,0.f,0.f};
        f32x4 a2 = {0.f,0.f,0.f,0.f}, a3 = {0.f,0.f,0.f,0.f};
        #define MSTEP(BQ, KT) { f16x8 bf = __builtin_bit_cast(f16x8, BQ);                  \
            a0 = __builtin_amdgcn_mfma_f32_16x16x32_f16(afrag[0][KT], bf, a0, 0, 0, 0);    \
            a1 = __builtin_amdgcn_mfma_f32_16x16x32_f16(afrag[1][KT], bf, a1, 0, 0, 0);    \
            a2 = __builtin_amdgcn_mfma_f32_16x16x32_f16(afrag[2][KT], bf, a2, 0, 0, 0);    \
            a3 = __builtin_amdgcn_mfma_f32_16x16x32_f16(afrag[3][KT], bf, a3, 0, 0, 0); }
        MSTEP(bq0, 0) MSTEP(bq1, 1) MSTEP(bq2, 2) MSTEP(bq3, 3)
        MSTEP(bq4, 4) MSTEP(bq5, 5) MSTEP(bq6, 6) MSTEP(bq7, 7)
        #undef MSTEP

        // epilogue: tanh + EMA, all lanes on their own batch b
        #pragma unroll
        for (int r = 0; r < 4; ++r) {
            hreg[0][r] = alpha * hreg[0][r] + onema * fast_tanh(a0[r] + ec[0][r]);
            hreg[1][r] = alpha * hreg[1][r] + onema * fast_tanh(a1[r] + ec[1][r]);
            hreg[2][r] = alpha * hreg[2][r] + onema * fast_tanh(a2[r] + ec[2][r]);
            hreg[3][r] = alpha * hreg[3][r] + onema * fast_tanh(a3[r] + ec[3][r]);
        }
        // h -> LDS (next buffer) + optional in-place global h_seq store
        #pragma unroll
        for (int mt = 0; mt < 4; ++mt) {
            uint2 p = { pkrtz(hreg[mt][0], hreg[mt][1]), pkrtz(hreg[mt][2], hreg[mt][3]) };
            *(uint2*)(wb + wroff + mt * 32) = p;
            if (write_all) *(f32x4*)(sp + mt * 16) = hreg[mt];
        }
        sp += 256;
        barrier_lds_only();   // lgkmcnt(0)+s_barrier; global ops stay in flight
        #pragma unroll
        for (int mt = 0; mt < 4; ++mt) { ec[mt] = e1[mt]; e1[mt] = e2[mt]; }
    };

    for (int t = 0; t < SEQ; t += 2) {
        step(std::integral_constant<int, 0>{}, t);
        step(std::integral_constant<int, 1>{}, t + 1);
    }

    #pragma unroll
    for (int mt = 0; mt < 4; ++mt)
        *(f32x4*)(h_carry + b * 256 + wave * 64 + mt * 16 + q * 4) = hreg[mt];
}

// ---------------- final projection from h_carry ----------------
__global__ __launch_bounds__(256) void outproj_kernel(
    const float* __restrict__ h_carry, const float* __restrict__ ow, const float* __restrict__ ob,
    float* __restrict__ out)
{
    __shared__ float h_l[256];
    __shared__ float p_lds[4][64];
    int b = blockIdx.x;
    int tid = threadIdx.x;
    h_l[tid] = h_carry[b * 256 + tid];
    __syncthreads();
    int o = tid & 63, qq = tid >> 6;
    float s = 0.f;
    const float4* wp = (const float4*)(ow + o * 256 + qq * 64);
    const float4* hp = (const float4*)(h_l + qq * 64);
    #pragma unroll
    for (int m = 0; m < 16; ++m) {
        float4 wv = wp[m]; float4 hv = hp[m];
        s = fmaf(wv.x, hv.x, s); s = fmaf(wv.y, hv.y, s);
        s = fmaf(wv.z, hv.z, s); s = fmaf(wv.w, hv.w, s);
    }
    p_lds[qq][o] = s;
    __syncthreads();
    if (tid < 64)
        out[b * 64 + tid] = p_lds[0][tid] + p_lds[1][tid] + p_lds[2][tid] + p_lds[3][tid] + ob[tid];
}

extern "C" void kernel_launch(void* const* d_in, const int* in_sizes, int n_in,
                              void* d_out, int out_size, void* d_ws, size_t ws_size,
                              hipStream_t stream)
{
    const float* x     = (const float*)d_in[0];
    const float* cw1   = (const float*)d_in[1];
    const float* cb1   = (const float*)d_in[2];
    const float* cw2   = (const float*)d_in[3];
    const float* cb2   = (const float*)d_in[4];
    const float* pw    = (const float*)d_in[5];
    const float* pb    = (const float*)d_in[6];
    const float* W_rec = (const float*)d_in[7];
    const float* W_in  = (const float*)d_in[8];
    const float* bias  = (const float*)d_in[9];
    const float* tau_b = (const float*)d_in[10];
    const float* tmw   = (const float*)d_in[11];
    const float* tmb   = (const float*)d_in[12];
    const float* ow    = (const float*)d_in[13];
    const float* ob    = (const float*)d_in[14];
    float* out = (float*)d_out;

    char* ws = (char*)d_ws;
    float* alphas  = (float*)ws;                       // 192 f
    float* h_carry = (float*)(ws + 4096);              // 64*256 f
    float* bf      = (float*)(ws + 69632);             // 256 f
    float* Wf      = (float*)(ws + 70656);             // 256*128 f
    float* buf     = (float*)(ws + 1048576);           // [64][2048][256] f32 = 134.2MB

    const int M = BATCH * SEQ;          // 131072 rows
    const int ROWS_PER_WG = M / 256;    // 512

    prep_kernel<<<64, 1024, 0, stream>>>(x, cw1, cb1, cw2, cb2, tau_b, tmw, tmb, alphas);
    wf_kernel<<<256, 128, 0, stream>>>(W_in, pw, pb, bias, Wf, bf);

    // layer 0 ext = x @ Wf.T + bf  (input projection fused away)
    gemm_stream<2, 1><<<256, 512, 0, stream>>>(x, Wf, bf, buf, ROWS_PER_WG);
    scan_kernel<<<4, 256, 0, stream>>>(buf, W_rec, alphas, h_carry, 0, 1);

    gemm_stream<4, 2><<<256, 512, 0, stream>>>(buf, W_in + (size_t)1 * HIDDEN * HIDDEN,
                                               bias + 1 * HIDDEN, buf, ROWS_PER_WG);
    scan_kernel<<<4, 256, 0, stream>>>(buf, W_rec + (size_t)1 * HIDDEN * HIDDEN,
                                       alphas + 64, h_carry, 1, 1);

    gemm_stream<4, 2><<<256, 512, 0, stream>>>(buf, W_in + (size_t)2 * HIDDEN * HIDDEN,
                                               bias + 2 * HIDDEN, buf, ROWS_PER_WG);
    scan_kernel<<<4, 256, 0, stream>>>(buf, W_rec + (size_t)2 * HIDDEN * HIDDEN,
                                       alphas + 128, h_carry, 2, 0);

    outproj_kernel<<<64, 256, 0, stream>>>(h_carry, ow, ob, out);
}